// Round 6
// baseline (446.757 us; speedup 1.0000x reference)
//
#include <hip/hip_runtime.h>
#include <hip/hip_bf16.h>
#include <math.h>

#define BATCH   4
#define N_KP    1024
#define C_DIM   128
#define HW_     256
#define M_CELLS 1024
#define BIGV    10.0f
#define EPSV    1e-8f

__device__ inline float wsum(float v) {
#pragma unroll
    for (int off = 32; off > 0; off >>= 1) v += __shfl_xor(v, off, 64);
    return v;
}

// branchless insert of x into ascending sorted-8 (keep 8 smallest)
__device__ inline void ins8(float s[8], float x) {
    s[7] = fminf(s[7], x);
#pragma unroll
    for (int t = 7; t >= 1; --t) {
        float lo = fminf(s[t - 1], s[t]);
        float hi = fmaxf(s[t - 1], s[t]);
        s[t - 1] = lo; s[t] = hi;
    }
}

#define CE(a, b) { float _lo = fminf(a, b), _hi = fmaxf(a, b); a = _lo; b = _hi; }

__device__ inline void merge64(float s[8]) {
#pragma unroll
    for (int d = 1; d < 64; d <<= 1) {
        float p[8];
#pragma unroll
        for (int i = 0; i < 8; ++i) p[i] = __shfl_xor(s[i], d, 64);
        float m[8];
#pragma unroll
        for (int i = 0; i < 8; ++i) m[i] = fminf(s[i], p[7 - i]);
        CE(m[0], m[4]); CE(m[1], m[5]); CE(m[2], m[6]); CE(m[3], m[7]);
        CE(m[0], m[2]); CE(m[1], m[3]); CE(m[4], m[6]); CE(m[5], m[7]);
        CE(m[0], m[1]); CE(m[2], m[3]); CE(m[4], m[5]); CE(m[6], m[7]);
#pragma unroll
        for (int i = 0; i < 8; ++i) s[i] = m[i];
    }
}

__device__ inline float packkey(float v, int j) {
    return __uint_as_float((__float_as_uint(v) & 0xFFFFFC00u) | (unsigned)j);
}

__device__ inline unsigned bf16rne(float x) {
    unsigned u = __float_as_uint(x);
    return (u + 0x7FFFu + ((u >> 16) & 1u)) >> 16;
}
__device__ inline float bflo(unsigned q) { return __uint_as_float(q << 16); }
__device__ inline float bfhi(unsigned q) { return __uint_as_float(q & 0xFFFF0000u); }

// ---------------- K1: a = l2n(kp1_desc) + visibility ----------------
__global__ __launch_bounds__(64) void k_prep(const float* __restrict__ desc,
                                             const float* __restrict__ kp1,
                                             const float* __restrict__ homo,
                                             float* __restrict__ a,
                                             float* __restrict__ vis,
                                             float* __restrict__ acc) {
    int row = blockIdx.x;
    int l = threadIdx.x;
    const float2* src = (const float2*)(desc + (size_t)row * C_DIM);
    float2 v = src[l];
    float ss = wsum(v.x * v.x + v.y * v.y);
    float nrm = sqrtf(ss) + EPSV;
    float2* dst = (float2*)(a + (size_t)row * C_DIM);
    dst[l] = make_float2(v.x / nrm, v.y / nrm);
    if (l == 0) {
        int b = row >> 10;
        float x = kp1[(size_t)row * 2];
        float y = kp1[(size_t)row * 2 + 1];
        const float* h = homo + b * 9;
        float u = h[0] * x + h[1] * y + h[2];
        float vv = h[3] * x + h[4] * y + h[5];
        float w = h[6] * x + h[7] * y + h[8];
        float wx_ = u / (w + EPSV);
        float wy_ = vv / (w + EPSV);
        float viz = (wx_ >= 0.f && wx_ <= (float)(HW_ - 1) &&
                     wy_ >= 0.f && wy_ <= (float)(HW_ - 1)) ? 1.f : 0.f;
        vis[row] = viz;
        atomicAdd(&acc[2], viz);
    }
}

// ---------------- K2: transpose desc2 (B,C,H,W) fp32 -> (B,H,W,C) packed bf16 ----------------
__global__ __launch_bounds__(256) void k_tr(const float* __restrict__ d2,
                                            unsigned int* __restrict__ d2t) {
    __shared__ float tile[64 * 65];
    int by = blockIdx.z;                 // b*256 + y
    int b = by >> 8, y = by & 255;
    int c0 = blockIdx.y * 64;
    int x0 = blockIdx.x * 64;
    int t = threadIdx.x;
    int tx = t & 63, tq = t >> 6;
#pragma unroll
    for (int i = 0; i < 16; ++i) {
        int c = 4 * i + tq;
        tile[c * 65 + tx] = d2[(size_t)((b * C_DIM + c0 + c) * HW_ + y) * HW_ + x0 + tx];
    }
    __syncthreads();
    int u = t & 31, xq = t >> 5;
#pragma unroll
    for (int i = 0; i < 8; ++i) {
        int x = 8 * i + xq;
        unsigned b0 = bf16rne(tile[(2 * u) * 65 + x]);
        unsigned b1 = bf16rne(tile[(2 * u + 1) * 65 + x]);
        d2t[(size_t)((b * HW_ + y) * HW_ + x0 + x) * 64 + (c0 >> 1) + u] = b0 | (b1 << 16);
    }
}

// ---------------- K3: fused wa (id<4096) + gd (id>=4096) gather from d2t ----------------
__global__ __launch_bounds__(64) void k_gather(const float* __restrict__ wkp,
                                               const unsigned int* __restrict__ d2t,
                                               const float* __restrict__ a,
                                               float* __restrict__ waT,   // (B,C,N)
                                               float* __restrict__ waR,   // (B,N,C)
                                               float* __restrict__ gdT,   // (B,C,M)
                                               float* __restrict__ pos) {
    int id = blockIdx.x;
    int l = threadIdx.x;
    if (id < BATCH * N_KP) {
        int row = id;
        int b = row >> 10, n = row & 1023;
        float px = wkp[(size_t)row * 2];
        float py = wkp[(size_t)row * 2 + 1];
        float x = fminf(fmaxf(px, 0.f), (float)(HW_ - 1));
        float y = fminf(fmaxf(py, 0.f), (float)(HW_ - 1));
        float x0f = floorf(x), y0f = floorf(y);
        float wx = x - x0f, wy = y - y0f;
        int x0 = (int)x0f, y0 = (int)y0f;
        int x1 = min(x0 + 1, HW_ - 1), y1 = min(y0 + 1, HW_ - 1);
        float w00 = (1.f - wy) * (1.f - wx);
        float w01 = (1.f - wy) * wx;
        float w10 = wy * (1.f - wx);
        float w11 = wy * wx;
        const unsigned* P = d2t + (size_t)b * HW_ * HW_ * 64;
        unsigned q00 = P[(size_t)(y0 * HW_ + x0) * 64 + l];
        unsigned q01 = P[(size_t)(y0 * HW_ + x1) * 64 + l];
        unsigned q10 = P[(size_t)(y1 * HW_ + x0) * 64 + l];
        unsigned q11 = P[(size_t)(y1 * HW_ + x1) * 64 + l];
        float v0 = bflo(q00) * w00 + bflo(q01) * w01 + bflo(q10) * w10 + bflo(q11) * w11;
        float v1 = bfhi(q00) * w00 + bfhi(q01) * w01 + bfhi(q10) * w10 + bfhi(q11) * w11;
        float ss = wsum(v0 * v0 + v1 * v1);
        float nrm = sqrtf(ss) + EPSV;
        float wv0 = v0 / nrm, wv1 = v1 / nrm;
        waT[(size_t)(b * C_DIM + 2 * l) * N_KP + n]     = wv0;
        waT[(size_t)(b * C_DIM + 2 * l + 1) * N_KP + n] = wv1;
        ((float2*)(waR + (size_t)row * C_DIM))[l] = make_float2(wv0, wv1);
        float2 av = ((const float2*)(a + (size_t)row * C_DIM))[l];
        float d0 = av.x - wv0, d1 = av.y - wv1;
        float pp = wsum(d0 * d0 + d1 * d1);
        if (l == 0) pos[row] = sqrtf(pp);
    } else {
        int idx = id - BATCH * N_KP;
        int b = idx >> 10, m = idx & 1023;
        int x0 = (m & 31) * 8 + 4;
        int y0 = (m >> 5) * 8 + 4;
        const unsigned* P = d2t + (size_t)b * HW_ * HW_ * 64;
        unsigned q = P[(size_t)(y0 * HW_ + x0) * 64 + l];
        float v0 = bflo(q), v1 = bfhi(q);
        float ss = wsum(v0 * v0 + v1 * v1);
        float nrm = sqrtf(ss) + EPSV;
        gdT[(size_t)(b * C_DIM + 2 * l) * M_CELLS + m]     = v0 / nrm;
        gdT[(size_t)(b * C_DIM + 2 * l + 1) * M_CELLS + m] = v1 / nrm;
    }
}

// ---------------- K4: distance matrix -> global (no LDS, register prefetch) ----------------
// z==0: neg (A=a, G=gdT);  z==1: d2m (A=waR, G=waT)
__global__ __launch_bounds__(256, 4) void k_dist(const float* __restrict__ a,
                                                 const float* __restrict__ gdT,
                                                 const float* __restrict__ waT,
                                                 const float* __restrict__ waR,
                                                 const float* __restrict__ wkp,
                                                 float* __restrict__ mat) {
    int b = blockIdx.y;
    int n0 = blockIdx.x * 8;
    int t = threadIdx.x;
    int zsel = blockIdx.z;
    const float* A = (zsel == 0 ? a : waR) + (size_t)(b * N_KP + n0) * C_DIM;
    const float4* Gp = (const float4*)((zsel == 0 ? gdT : waT) + (size_t)b * C_DIM * 1024) + t;
    float4 s[8];
#pragma unroll
    for (int r = 0; r < 8; ++r) s[r] = make_float4(0.f, 0.f, 0.f, 0.f);
    float4 g[4], gn[4];
#pragma unroll
    for (int i = 0; i < 4; ++i) g[i] = Gp[(size_t)i * 256];
#pragma unroll 1
    for (int c = 0; c < C_DIM - 4; c += 4) {
#pragma unroll
        for (int i = 0; i < 4; ++i) gn[i] = Gp[(size_t)(c + 4 + i) * 256];
#pragma unroll
        for (int r = 0; r < 8; ++r) {
            float4 av = *(const float4*)(A + r * C_DIM + c);
            s[r].x += av.x * g[0].x + av.y * g[1].x + av.z * g[2].x + av.w * g[3].x;
            s[r].y += av.x * g[0].y + av.y * g[1].y + av.z * g[2].y + av.w * g[3].y;
            s[r].z += av.x * g[0].z + av.y * g[1].z + av.z * g[2].z + av.w * g[3].z;
            s[r].w += av.x * g[0].w + av.y * g[1].w + av.z * g[2].w + av.w * g[3].w;
        }
#pragma unroll
        for (int i = 0; i < 4; ++i) g[i] = gn[i];
    }
    {
        const int c = C_DIM - 4;
#pragma unroll
        for (int r = 0; r < 8; ++r) {
            float4 av = *(const float4*)(A + r * C_DIM + c);
            s[r].x += av.x * g[0].x + av.y * g[1].x + av.z * g[2].x + av.w * g[3].x;
            s[r].y += av.x * g[0].y + av.y * g[1].y + av.z * g[2].y + av.w * g[3].y;
            s[r].z += av.x * g[0].z + av.y * g[1].z + av.z * g[2].z + av.w * g[3].z;
            s[r].w += av.x * g[0].w + av.y * g[1].w + av.z * g[2].w + av.w * g[3].w;
        }
    }
    int j0 = 4 * t;
    float* out = mat + (size_t)((zsel * BATCH + b) * N_KP + n0) * 1024;
    if (zsel == 0) {
        float cgx0 = (float)(j0 & 31) * 8.0f + 4.0f,       cgy0 = (float)(j0 >> 5) * 8.0f + 4.0f;
        float cgx1 = (float)((j0 + 1) & 31) * 8.0f + 4.0f, cgy1 = (float)((j0 + 1) >> 5) * 8.0f + 4.0f;
        float cgx2 = (float)((j0 + 2) & 31) * 8.0f + 4.0f, cgy2 = (float)((j0 + 2) >> 5) * 8.0f + 4.0f;
        float cgx3 = (float)((j0 + 3) & 31) * 8.0f + 4.0f, cgy3 = (float)((j0 + 3) >> 5) * 8.0f + 4.0f;
#pragma unroll
        for (int r = 0; r < 8; ++r) {
            float wx = wkp[(size_t)(b * N_KP + n0 + r) * 2];
            float wy = wkp[(size_t)(b * N_KP + n0 + r) * 2 + 1];
            float4 d;
            d.x = sqrtf(fmaxf(2.f - 2.f * s[r].x, 0.f) + EPSV);
            d.y = sqrtf(fmaxf(2.f - 2.f * s[r].y, 0.f) + EPSV);
            d.z = sqrtf(fmaxf(2.f - 2.f * s[r].z, 0.f) + EPSV);
            d.w = sqrtf(fmaxf(2.f - 2.f * s[r].w, 0.f) + EPSV);
            float dx, dy;
            dx = wx - cgx0; dy = wy - cgy0; if (dx * dx + dy * dy < 256.f) d.x = BIGV;
            dx = wx - cgx1; dy = wy - cgy1; if (dx * dx + dy * dy < 256.f) d.y = BIGV;
            dx = wx - cgx2; dy = wy - cgy2; if (dx * dx + dy * dy < 256.f) d.z = BIGV;
            dx = wx - cgx3; dy = wy - cgy3; if (dx * dx + dy * dy < 256.f) d.w = BIGV;
            ((float4*)(out + r * 1024))[t] = d;
        }
    } else {
        float4 wjA = ((const float4*)(wkp + (size_t)b * N_KP * 2))[2 * t];
        float4 wjB = ((const float4*)(wkp + (size_t)b * N_KP * 2))[2 * t + 1];
#pragma unroll
        for (int r = 0; r < 8; ++r) {
            int n = n0 + r;
            float wx = wkp[(size_t)(b * N_KP + n) * 2];
            float wy = wkp[(size_t)(b * N_KP + n) * 2 + 1];
            float4 d;
            d.x = sqrtf(fmaxf(2.f - 2.f * s[r].x, 0.f) + EPSV);
            d.y = sqrtf(fmaxf(2.f - 2.f * s[r].y, 0.f) + EPSV);
            d.z = sqrtf(fmaxf(2.f - 2.f * s[r].z, 0.f) + EPSV);
            d.w = sqrtf(fmaxf(2.f - 2.f * s[r].w, 0.f) + EPSV);
            float dx, dy;
            dx = wx - wjA.x; dy = wy - wjA.y; if (dx * dx + dy * dy < 256.f || n == j0)     d.x = BIGV;
            dx = wx - wjA.z; dy = wy - wjA.w; if (dx * dx + dy * dy < 256.f || n == j0 + 1) d.y = BIGV;
            dx = wx - wjB.x; dy = wy - wjB.y; if (dx * dx + dy * dy < 256.f || n == j0 + 2) d.z = BIGV;
            dx = wx - wjB.z; dy = wy - wjB.w; if (dx * dx + dy * dy < 256.f || n == j0 + 3) d.w = BIGV;
            ((float4*)(out + r * 1024))[t] = d;
        }
    }
}

// ---------------- K5: selection + loss (no LDS; 1 row/wave) ----------------
__global__ __launch_bounds__(256) void k_sel(const float* __restrict__ mat,
                                             const float* __restrict__ a,
                                             const float* __restrict__ pos,
                                             const float* __restrict__ vis,
                                             float* __restrict__ acc) {
    int zsel = blockIdx.y;
    int r4 = blockIdx.x * 4 + (threadIdx.x >> 6);   // row in [0,4096)
    int b = r4 >> 10;
    int l = threadIdx.x & 63;
    const float4* dr = (const float4*)(mat + (size_t)(zsel * BATCH * N_KP + r4) * 1024);
    float s8[8];
#pragma unroll
    for (int k = 0; k < 8; ++k) s8[k] = 1e30f;
    if (zsel == 0) {
        float4 v0 = dr[l], v1 = dr[l + 64], v2 = dr[l + 128], v3 = dr[l + 192];
        ins8(s8, v0.x); ins8(s8, v0.y); ins8(s8, v0.z); ins8(s8, v0.w);
        ins8(s8, v1.x); ins8(s8, v1.y); ins8(s8, v1.z); ins8(s8, v1.w);
        ins8(s8, v2.x); ins8(s8, v2.y); ins8(s8, v2.z); ins8(s8, v2.w);
        ins8(s8, v3.x); ins8(s8, v3.y); ins8(s8, v3.z); ins8(s8, v3.w);
        merge64(s8);
        if (l == 0) {
            float p = pos[r4];
            float sum = 0.f;
#pragma unroll
            for (int q = 0; q < 8; ++q) sum += fmaxf(p - s8[q] + 1.0f, 0.f);
            atomicAdd(&acc[0], sum * vis[r4]);
        }
    } else {
#pragma unroll
        for (int k = 0; k < 4; ++k) {
            float4 v = dr[l + 64 * k];
            int j = 4 * (l + 64 * k);
            ins8(s8, packkey(v.x, j));
            ins8(s8, packkey(v.y, j + 1));
            ins8(s8, packkey(v.z, j + 2));
            ins8(s8, packkey(v.w, j + 3));
        }
        merge64(s8);
        float2 av = ((const float2*)(a + (size_t)r4 * C_DIM))[l];
        float dot[8];
#pragma unroll
        for (int q = 0; q < 8; ++q) {
            int j = (int)(__float_as_uint(s8[q]) & 1023u);
            float2 jv = ((const float2*)(a + (size_t)(b * N_KP + j) * C_DIM))[l];
            dot[q] = av.x * jv.x + av.y * jv.y;
        }
#pragma unroll
        for (int q = 0; q < 8; ++q) dot[q] = wsum(dot[q]);
        float ss2 = 0.f;
#pragma unroll
        for (int q = 0; q < 8; ++q) {
            float d2s = __uint_as_float(__float_as_uint(s8[q]) & 0xFFFFFC00u);
            float d1 = sqrtf(fmaxf(2.f - 2.f * dot[q], 0.f) + EPSV);
            float okv = (d2s < 5.0f) ? 1.f : 0.f;
            float diff = (d1 - d2s) * okv;
            ss2 += diff * diff;
        }
        if (l == 0) atomicAdd(&acc[1], sqrtf(ss2 + EPSV) * vis[r4]);
    }
}

// ---------------- K6: finalize ----------------
__global__ void k_fin(const float* __restrict__ acc, float* __restrict__ out) {
    float cnt = fmaxf(acc[2], 1.0f);
    float fos = acc[0] / (cnt * 8.0f);
    float sos = acc[1] / cnt;
    out[0] = fos + sos;
}

extern "C" void kernel_launch(void* const* d_in, const int* in_sizes, int n_in,
                              void* d_out, int out_size, void* d_ws, size_t ws_size,
                              hipStream_t stream) {
    (void)in_sizes; (void)n_in; (void)out_size; (void)ws_size;
    const float* kp1   = (const float*)d_in[0];
    const float* wkp   = (const float*)d_in[1];
    const float* kdesc = (const float*)d_in[2];
    const float* desc2 = (const float*)d_in[3];
    const float* homo  = (const float*)d_in[4];

    float* ws  = (float*)d_ws;
    float* acc = ws;                                   // [0]=fos [1]=sos [2]=cnt
    float* a   = ws + 16;                              // (B,N,C)
    float* waT = a + (size_t)BATCH * N_KP * C_DIM;     // (B,C,N)
    float* waR = waT + (size_t)BATCH * C_DIM * N_KP;   // (B,N,C)
    float* gdT = waR + (size_t)BATCH * N_KP * C_DIM;   // (B,C,M)
    float* pos = gdT + (size_t)BATCH * C_DIM * M_CELLS;
    float* vis = pos + BATCH * N_KP;
    unsigned int* d2t = (unsigned int*)(vis + BATCH * N_KP);   // (B,H,W,64) packed bf16, 64 MB
    float* mat = (float*)(d2t + (size_t)BATCH * HW_ * HW_ * 64); // (2,B,N,1024) fp32, 32 MB

    hipMemsetAsync(acc, 0, 16 * sizeof(float), stream);
    k_prep<<<BATCH * N_KP, 64, 0, stream>>>(kdesc, kp1, homo, a, vis, acc);
    k_tr<<<dim3(HW_ / 64, C_DIM / 64, BATCH * HW_), 256, 0, stream>>>(desc2, d2t);
    k_gather<<<2 * BATCH * N_KP, 64, 0, stream>>>(wkp, d2t, a, waT, waR, gdT, pos);
    k_dist<<<dim3(N_KP / 8, BATCH, 2), 256, 0, stream>>>(a, gdT, waT, waR, wkp, mat);
    k_sel<<<dim3(N_KP * BATCH / 4, 2), 256, 0, stream>>>(mat, a, pos, vis, acc);
    k_fin<<<1, 1, 0, stream>>>(acc, (float*)d_out);
}

// Round 7
// 299.466 us; speedup vs baseline: 1.4918x; 1.4918x over previous
//
#include <hip/hip_runtime.h>
#include <hip/hip_bf16.h>
#include <math.h>

#define BATCH   4
#define N_KP    1024
#define C_DIM   128
#define HW_     256
#define M_CELLS 1024
#define BIGV    10.0f
#define EPSV    1e-8f

__device__ inline float wsum(float v) {
#pragma unroll
    for (int off = 32; off > 0; off >>= 1) v += __shfl_xor(v, off, 64);
    return v;
}

// branchless insert of x into ascending sorted-8 (keep 8 smallest)
__device__ inline void ins8(float s[8], float x) {
    s[7] = fminf(s[7], x);
#pragma unroll
    for (int t = 7; t >= 1; --t) {
        float lo = fminf(s[t - 1], s[t]);
        float hi = fmaxf(s[t - 1], s[t]);
        s[t - 1] = lo; s[t] = hi;
    }
}

#define CE(a, b) { float _lo = fminf(a, b), _hi = fmaxf(a, b); a = _lo; b = _hi; }

__device__ inline void merge64(float s[8]) {
#pragma unroll
    for (int d = 1; d < 64; d <<= 1) {
        float p[8];
#pragma unroll
        for (int i = 0; i < 8; ++i) p[i] = __shfl_xor(s[i], d, 64);
        float m[8];
#pragma unroll
        for (int i = 0; i < 8; ++i) m[i] = fminf(s[i], p[7 - i]);
        CE(m[0], m[4]); CE(m[1], m[5]); CE(m[2], m[6]); CE(m[3], m[7]);
        CE(m[0], m[2]); CE(m[1], m[3]); CE(m[4], m[6]); CE(m[5], m[7]);
        CE(m[0], m[1]); CE(m[2], m[3]); CE(m[4], m[5]); CE(m[6], m[7]);
#pragma unroll
        for (int i = 0; i < 8; ++i) s[i] = m[i];
    }
}

__device__ inline float packkey(float v, int j) {
    return __uint_as_float((__float_as_uint(v) & 0xFFFFFC00u) | (unsigned)j);
}

__device__ inline unsigned bf16rne(float x) {
    unsigned u = __float_as_uint(x);
    return (u + 0x7FFFu + ((u >> 16) & 1u)) >> 16;
}
__device__ inline float bflo(unsigned q) { return __uint_as_float(q << 16); }
__device__ inline float bfhi(unsigned q) { return __uint_as_float(q & 0xFFFF0000u); }

// ---------------- K1: a = l2n(kp1_desc) + visibility (NO atomics) ----------------
__global__ __launch_bounds__(64) void k_prep(const float* __restrict__ desc,
                                             const float* __restrict__ kp1,
                                             const float* __restrict__ homo,
                                             float* __restrict__ a,
                                             float* __restrict__ vis) {
    int row = blockIdx.x;
    int l = threadIdx.x;
    const float2* src = (const float2*)(desc + (size_t)row * C_DIM);
    float2 v = src[l];
    float ss = wsum(v.x * v.x + v.y * v.y);
    float nrm = sqrtf(ss) + EPSV;
    float2* dst = (float2*)(a + (size_t)row * C_DIM);
    dst[l] = make_float2(v.x / nrm, v.y / nrm);
    if (l == 0) {
        int b = row >> 10;
        float x = kp1[(size_t)row * 2];
        float y = kp1[(size_t)row * 2 + 1];
        const float* h = homo + b * 9;
        float u = h[0] * x + h[1] * y + h[2];
        float vv = h[3] * x + h[4] * y + h[5];
        float w = h[6] * x + h[7] * y + h[8];
        float wx_ = u / (w + EPSV);
        float wy_ = vv / (w + EPSV);
        float viz = (wx_ >= 0.f && wx_ <= (float)(HW_ - 1) &&
                     wy_ >= 0.f && wy_ <= (float)(HW_ - 1)) ? 1.f : 0.f;
        vis[row] = viz;
    }
}

// ---------------- K2: transpose desc2 (B,C,H,W) fp32 -> (B,H,W,C) packed bf16 ----------------
__global__ __launch_bounds__(256) void k_tr(const float* __restrict__ d2,
                                            unsigned int* __restrict__ d2t) {
    __shared__ float tile[64 * 65];
    int by = blockIdx.z;                 // b*256 + y
    int b = by >> 8, y = by & 255;
    int c0 = blockIdx.y * 64;
    int x0 = blockIdx.x * 64;
    int t = threadIdx.x;
    int tx = t & 63, tq = t >> 6;
#pragma unroll
    for (int i = 0; i < 16; ++i) {
        int c = 4 * i + tq;
        tile[c * 65 + tx] = d2[(size_t)((b * C_DIM + c0 + c) * HW_ + y) * HW_ + x0 + tx];
    }
    __syncthreads();
    int u = t & 31, xq = t >> 5;
#pragma unroll
    for (int i = 0; i < 8; ++i) {
        int x = 8 * i + xq;
        unsigned b0 = bf16rne(tile[(2 * u) * 65 + x]);
        unsigned b1 = bf16rne(tile[(2 * u + 1) * 65 + x]);
        d2t[(size_t)((b * HW_ + y) * HW_ + x0 + x) * 64 + (c0 >> 1) + u] = b0 | (b1 << 16);
    }
}

// ---------------- K3: fused wa (id<4096) + gd (id>=4096) gather from d2t ----------------
__global__ __launch_bounds__(64) void k_gather(const float* __restrict__ wkp,
                                               const unsigned int* __restrict__ d2t,
                                               const float* __restrict__ a,
                                               float* __restrict__ waT,   // (B,C,N)
                                               float* __restrict__ waR,   // (B,N,C)
                                               float* __restrict__ gdT,   // (B,C,M)
                                               float* __restrict__ pos) {
    int id = blockIdx.x;
    int l = threadIdx.x;
    if (id < BATCH * N_KP) {
        int row = id;
        int b = row >> 10, n = row & 1023;
        float px = wkp[(size_t)row * 2];
        float py = wkp[(size_t)row * 2 + 1];
        float x = fminf(fmaxf(px, 0.f), (float)(HW_ - 1));
        float y = fminf(fmaxf(py, 0.f), (float)(HW_ - 1));
        float x0f = floorf(x), y0f = floorf(y);
        float wx = x - x0f, wy = y - y0f;
        int x0 = (int)x0f, y0 = (int)y0f;
        int x1 = min(x0 + 1, HW_ - 1), y1 = min(y0 + 1, HW_ - 1);
        float w00 = (1.f - wy) * (1.f - wx);
        float w01 = (1.f - wy) * wx;
        float w10 = wy * (1.f - wx);
        float w11 = wy * wx;
        const unsigned* P = d2t + (size_t)b * HW_ * HW_ * 64;
        unsigned q00 = P[(size_t)(y0 * HW_ + x0) * 64 + l];
        unsigned q01 = P[(size_t)(y0 * HW_ + x1) * 64 + l];
        unsigned q10 = P[(size_t)(y1 * HW_ + x0) * 64 + l];
        unsigned q11 = P[(size_t)(y1 * HW_ + x1) * 64 + l];
        float v0 = bflo(q00) * w00 + bflo(q01) * w01 + bflo(q10) * w10 + bflo(q11) * w11;
        float v1 = bfhi(q00) * w00 + bfhi(q01) * w01 + bfhi(q10) * w10 + bfhi(q11) * w11;
        float ss = wsum(v0 * v0 + v1 * v1);
        float nrm = sqrtf(ss) + EPSV;
        float wv0 = v0 / nrm, wv1 = v1 / nrm;
        waT[(size_t)(b * C_DIM + 2 * l) * N_KP + n]     = wv0;
        waT[(size_t)(b * C_DIM + 2 * l + 1) * N_KP + n] = wv1;
        ((float2*)(waR + (size_t)row * C_DIM))[l] = make_float2(wv0, wv1);
        float2 av = ((const float2*)(a + (size_t)row * C_DIM))[l];
        float d0 = av.x - wv0, d1 = av.y - wv1;
        float pp = wsum(d0 * d0 + d1 * d1);
        if (l == 0) pos[row] = sqrtf(pp);
    } else {
        int idx = id - BATCH * N_KP;
        int b = idx >> 10, m = idx & 1023;
        int x0 = (m & 31) * 8 + 4;
        int y0 = (m >> 5) * 8 + 4;
        const unsigned* P = d2t + (size_t)b * HW_ * HW_ * 64;
        unsigned q = P[(size_t)(y0 * HW_ + x0) * 64 + l];
        float v0 = bflo(q), v1 = bfhi(q);
        float ss = wsum(v0 * v0 + v1 * v1);
        float nrm = sqrtf(ss) + EPSV;
        gdT[(size_t)(b * C_DIM + 2 * l) * M_CELLS + m]     = v0 / nrm;
        gdT[(size_t)(b * C_DIM + 2 * l + 1) * M_CELLS + m] = v1 / nrm;
    }
}

// ---------------- K4: distance matrix -> global (no LDS, register prefetch) ----------------
// z==0: neg (A=a, G=gdT);  z==1: d2m (A=waR, G=waT)
__global__ __launch_bounds__(256, 4) void k_dist(const float* __restrict__ a,
                                                 const float* __restrict__ gdT,
                                                 const float* __restrict__ waT,
                                                 const float* __restrict__ waR,
                                                 const float* __restrict__ wkp,
                                                 float* __restrict__ mat) {
    int b = blockIdx.y;
    int n0 = blockIdx.x * 8;
    int t = threadIdx.x;
    int zsel = blockIdx.z;
    const float* A = (zsel == 0 ? a : waR) + (size_t)(b * N_KP + n0) * C_DIM;
    const float4* Gp = (const float4*)((zsel == 0 ? gdT : waT) + (size_t)b * C_DIM * 1024) + t;
    float4 s[8];
#pragma unroll
    for (int r = 0; r < 8; ++r) s[r] = make_float4(0.f, 0.f, 0.f, 0.f);
    float4 g[4], gn[4];
#pragma unroll
    for (int i = 0; i < 4; ++i) g[i] = Gp[(size_t)i * 256];
#pragma unroll 1
    for (int c = 0; c < C_DIM - 4; c += 4) {
#pragma unroll
        for (int i = 0; i < 4; ++i) gn[i] = Gp[(size_t)(c + 4 + i) * 256];
#pragma unroll
        for (int r = 0; r < 8; ++r) {
            float4 av = *(const float4*)(A + r * C_DIM + c);
            s[r].x += av.x * g[0].x + av.y * g[1].x + av.z * g[2].x + av.w * g[3].x;
            s[r].y += av.x * g[0].y + av.y * g[1].y + av.z * g[2].y + av.w * g[3].y;
            s[r].z += av.x * g[0].z + av.y * g[1].z + av.z * g[2].z + av.w * g[3].z;
            s[r].w += av.x * g[0].w + av.y * g[1].w + av.z * g[2].w + av.w * g[3].w;
        }
#pragma unroll
        for (int i = 0; i < 4; ++i) g[i] = gn[i];
    }
    {
        const int c = C_DIM - 4;
#pragma unroll
        for (int r = 0; r < 8; ++r) {
            float4 av = *(const float4*)(A + r * C_DIM + c);
            s[r].x += av.x * g[0].x + av.y * g[1].x + av.z * g[2].x + av.w * g[3].x;
            s[r].y += av.x * g[0].y + av.y * g[1].y + av.z * g[2].y + av.w * g[3].y;
            s[r].z += av.x * g[0].z + av.y * g[1].z + av.z * g[2].z + av.w * g[3].z;
            s[r].w += av.x * g[0].w + av.y * g[1].w + av.z * g[2].w + av.w * g[3].w;
        }
    }
    int j0 = 4 * t;
    float* out = mat + (size_t)((zsel * BATCH + b) * N_KP + n0) * 1024;
    if (zsel == 0) {
        float cgx0 = (float)(j0 & 31) * 8.0f + 4.0f,       cgy0 = (float)(j0 >> 5) * 8.0f + 4.0f;
        float cgx1 = (float)((j0 + 1) & 31) * 8.0f + 4.0f, cgy1 = (float)((j0 + 1) >> 5) * 8.0f + 4.0f;
        float cgx2 = (float)((j0 + 2) & 31) * 8.0f + 4.0f, cgy2 = (float)((j0 + 2) >> 5) * 8.0f + 4.0f;
        float cgx3 = (float)((j0 + 3) & 31) * 8.0f + 4.0f, cgy3 = (float)((j0 + 3) >> 5) * 8.0f + 4.0f;
#pragma unroll
        for (int r = 0; r < 8; ++r) {
            float wx = wkp[(size_t)(b * N_KP + n0 + r) * 2];
            float wy = wkp[(size_t)(b * N_KP + n0 + r) * 2 + 1];
            float4 d;
            d.x = sqrtf(fmaxf(2.f - 2.f * s[r].x, 0.f) + EPSV);
            d.y = sqrtf(fmaxf(2.f - 2.f * s[r].y, 0.f) + EPSV);
            d.z = sqrtf(fmaxf(2.f - 2.f * s[r].z, 0.f) + EPSV);
            d.w = sqrtf(fmaxf(2.f - 2.f * s[r].w, 0.f) + EPSV);
            float dx, dy;
            dx = wx - cgx0; dy = wy - cgy0; if (dx * dx + dy * dy < 256.f) d.x = BIGV;
            dx = wx - cgx1; dy = wy - cgy1; if (dx * dx + dy * dy < 256.f) d.y = BIGV;
            dx = wx - cgx2; dy = wy - cgy2; if (dx * dx + dy * dy < 256.f) d.z = BIGV;
            dx = wx - cgx3; dy = wy - cgy3; if (dx * dx + dy * dy < 256.f) d.w = BIGV;
            ((float4*)(out + r * 1024))[t] = d;
        }
    } else {
        float4 wjA = ((const float4*)(wkp + (size_t)b * N_KP * 2))[2 * t];
        float4 wjB = ((const float4*)(wkp + (size_t)b * N_KP * 2))[2 * t + 1];
#pragma unroll
        for (int r = 0; r < 8; ++r) {
            int n = n0 + r;
            float wx = wkp[(size_t)(b * N_KP + n) * 2];
            float wy = wkp[(size_t)(b * N_KP + n) * 2 + 1];
            float4 d;
            d.x = sqrtf(fmaxf(2.f - 2.f * s[r].x, 0.f) + EPSV);
            d.y = sqrtf(fmaxf(2.f - 2.f * s[r].y, 0.f) + EPSV);
            d.z = sqrtf(fmaxf(2.f - 2.f * s[r].z, 0.f) + EPSV);
            d.w = sqrtf(fmaxf(2.f - 2.f * s[r].w, 0.f) + EPSV);
            float dx, dy;
            dx = wx - wjA.x; dy = wy - wjA.y; if (dx * dx + dy * dy < 256.f || n == j0)     d.x = BIGV;
            dx = wx - wjA.z; dy = wy - wjA.w; if (dx * dx + dy * dy < 256.f || n == j0 + 1) d.y = BIGV;
            dx = wx - wjB.x; dy = wy - wjB.y; if (dx * dx + dy * dy < 256.f || n == j0 + 2) d.z = BIGV;
            dx = wx - wjB.z; dy = wy - wjB.w; if (dx * dx + dy * dy < 256.f || n == j0 + 3) d.w = BIGV;
            ((float4*)(out + r * 1024))[t] = d;
        }
    }
}

// ---------------- K5: selection + per-row loss -> plain stores (NO atomics) ----------------
__global__ __launch_bounds__(256) void k_sel(const float* __restrict__ mat,
                                             const float* __restrict__ a,
                                             const float* __restrict__ pos,
                                             const float* __restrict__ vis,
                                             float* __restrict__ fos_row,
                                             float* __restrict__ sos_row) {
    int zsel = blockIdx.y;
    int r4 = blockIdx.x * 4 + (threadIdx.x >> 6);   // row in [0,4096)
    int b = r4 >> 10;
    int l = threadIdx.x & 63;
    const float4* dr = (const float4*)(mat + (size_t)(zsel * BATCH * N_KP + r4) * 1024);
    float s8[8];
#pragma unroll
    for (int k = 0; k < 8; ++k) s8[k] = 1e30f;
    if (zsel == 0) {
        float4 v0 = dr[l], v1 = dr[l + 64], v2 = dr[l + 128], v3 = dr[l + 192];
        ins8(s8, v0.x); ins8(s8, v0.y); ins8(s8, v0.z); ins8(s8, v0.w);
        ins8(s8, v1.x); ins8(s8, v1.y); ins8(s8, v1.z); ins8(s8, v1.w);
        ins8(s8, v2.x); ins8(s8, v2.y); ins8(s8, v2.z); ins8(s8, v2.w);
        ins8(s8, v3.x); ins8(s8, v3.y); ins8(s8, v3.z); ins8(s8, v3.w);
        merge64(s8);
        if (l == 0) {
            float p = pos[r4];
            float sum = 0.f;
#pragma unroll
            for (int q = 0; q < 8; ++q) sum += fmaxf(p - s8[q] + 1.0f, 0.f);
            fos_row[r4] = sum * vis[r4];
        }
    } else {
#pragma unroll
        for (int k = 0; k < 4; ++k) {
            float4 v = dr[l + 64 * k];
            int j = 4 * (l + 64 * k);
            ins8(s8, packkey(v.x, j));
            ins8(s8, packkey(v.y, j + 1));
            ins8(s8, packkey(v.z, j + 2));
            ins8(s8, packkey(v.w, j + 3));
        }
        merge64(s8);
        float2 av = ((const float2*)(a + (size_t)r4 * C_DIM))[l];
        float dot[8];
#pragma unroll
        for (int q = 0; q < 8; ++q) {
            int j = (int)(__float_as_uint(s8[q]) & 1023u);
            float2 jv = ((const float2*)(a + (size_t)(b * N_KP + j) * C_DIM))[l];
            dot[q] = av.x * jv.x + av.y * jv.y;
        }
#pragma unroll
        for (int q = 0; q < 8; ++q) dot[q] = wsum(dot[q]);
        float ss2 = 0.f;
#pragma unroll
        for (int q = 0; q < 8; ++q) {
            float d2s = __uint_as_float(__float_as_uint(s8[q]) & 0xFFFFFC00u);
            float d1 = sqrtf(fmaxf(2.f - 2.f * dot[q], 0.f) + EPSV);
            float okv = (d2s < 5.0f) ? 1.f : 0.f;
            float diff = (d1 - d2s) * okv;
            ss2 += diff * diff;
        }
        if (l == 0) sos_row[r4] = sqrtf(ss2 + EPSV) * vis[r4];
    }
}

// ---------------- K6: deterministic reduction + finalize (single block) ----------------
__global__ __launch_bounds__(1024) void k_red(const float* __restrict__ vis,
                                              const float* __restrict__ fos_row,
                                              const float* __restrict__ sos_row,
                                              float* __restrict__ out) {
    __shared__ float sb[3][16];
    int t = threadIdx.x;
    float sv = 0.f, sf = 0.f, ss = 0.f;
    for (int i = t; i < BATCH * N_KP; i += 1024) {
        sv += vis[i];
        sf += fos_row[i];
        ss += sos_row[i];
    }
    sv = wsum(sv); sf = wsum(sf); ss = wsum(ss);
    int w = t >> 6, l = t & 63;
    if (l == 0) { sb[0][w] = sv; sb[1][w] = sf; sb[2][w] = ss; }
    __syncthreads();
    if (t == 0) {
        float cv = 0.f, cf = 0.f, cs = 0.f;
#pragma unroll
        for (int i = 0; i < 16; ++i) { cv += sb[0][i]; cf += sb[1][i]; cs += sb[2][i]; }
        float cnt = fmaxf(cv, 1.0f);
        out[0] = cf / (cnt * 8.0f) + cs / cnt;
    }
}

extern "C" void kernel_launch(void* const* d_in, const int* in_sizes, int n_in,
                              void* d_out, int out_size, void* d_ws, size_t ws_size,
                              hipStream_t stream) {
    (void)in_sizes; (void)n_in; (void)out_size; (void)ws_size;
    const float* kp1   = (const float*)d_in[0];
    const float* wkp   = (const float*)d_in[1];
    const float* kdesc = (const float*)d_in[2];
    const float* desc2 = (const float*)d_in[3];
    const float* homo  = (const float*)d_in[4];

    float* ws  = (float*)d_ws;
    float* a   = ws + 16;                              // (B,N,C)
    float* waT = a + (size_t)BATCH * N_KP * C_DIM;     // (B,C,N)
    float* waR = waT + (size_t)BATCH * C_DIM * N_KP;   // (B,N,C)
    float* gdT = waR + (size_t)BATCH * N_KP * C_DIM;   // (B,C,M)
    float* pos = gdT + (size_t)BATCH * C_DIM * M_CELLS;
    float* vis = pos + BATCH * N_KP;
    float* fos_row = vis + BATCH * N_KP;
    float* sos_row = fos_row + BATCH * N_KP;
    unsigned int* d2t = (unsigned int*)(sos_row + BATCH * N_KP);   // (B,H,W,64) packed bf16, 64 MB
    float* mat = (float*)(d2t + (size_t)BATCH * HW_ * HW_ * 64);   // (2,B,N,1024) fp32, 32 MB

    k_prep<<<BATCH * N_KP, 64, 0, stream>>>(kdesc, kp1, homo, a, vis);
    k_tr<<<dim3(HW_ / 64, C_DIM / 64, BATCH * HW_), 256, 0, stream>>>(desc2, d2t);
    k_gather<<<2 * BATCH * N_KP, 64, 0, stream>>>(wkp, d2t, a, waT, waR, gdT, pos);
    k_dist<<<dim3(N_KP / 8, BATCH, 2), 256, 0, stream>>>(a, gdT, waT, waR, wkp, mat);
    k_sel<<<dim3(N_KP * BATCH / 4, 2), 256, 0, stream>>>(mat, a, pos, vis, fos_row, sos_row);
    k_red<<<1, 1024, 0, stream>>>(vis, fos_row, sos_row, (float*)d_out);
}

// Round 8
// 276.355 us; speedup vs baseline: 1.6166x; 1.0836x over previous
//
#include <hip/hip_runtime.h>
#include <hip/hip_bf16.h>
#include <math.h>

#define BATCH   4
#define N_KP    1024
#define C_DIM   128
#define HW_     256
#define M_CELLS 1024
#define BIGV    10.0f
#define EPSV    1e-8f

typedef __attribute__((ext_vector_type(8))) short short8;
typedef __attribute__((ext_vector_type(4))) float f32x4;

__device__ inline float wsum(float v) {
#pragma unroll
    for (int off = 32; off > 0; off >>= 1) v += __shfl_xor(v, off, 64);
    return v;
}

// branchless insert of x into ascending sorted-8 (keep 8 smallest)
__device__ inline void ins8(float s[8], float x) {
    s[7] = fminf(s[7], x);
#pragma unroll
    for (int t = 7; t >= 1; --t) {
        float lo = fminf(s[t - 1], s[t]);
        float hi = fmaxf(s[t - 1], s[t]);
        s[t - 1] = lo; s[t] = hi;
    }
}

#define CE(a, b) { float _lo = fminf(a, b), _hi = fmaxf(a, b); a = _lo; b = _hi; }

__device__ inline void merge64(float s[8]) {
#pragma unroll
    for (int d = 1; d < 64; d <<= 1) {
        float p[8];
#pragma unroll
        for (int i = 0; i < 8; ++i) p[i] = __shfl_xor(s[i], d, 64);
        float m[8];
#pragma unroll
        for (int i = 0; i < 8; ++i) m[i] = fminf(s[i], p[7 - i]);
        CE(m[0], m[4]); CE(m[1], m[5]); CE(m[2], m[6]); CE(m[3], m[7]);
        CE(m[0], m[2]); CE(m[1], m[3]); CE(m[4], m[6]); CE(m[5], m[7]);
        CE(m[0], m[1]); CE(m[2], m[3]); CE(m[4], m[5]); CE(m[6], m[7]);
#pragma unroll
        for (int i = 0; i < 8; ++i) s[i] = m[i];
    }
}

__device__ inline float packkey(float v, int j) {
    return __uint_as_float((__float_as_uint(v) & 0xFFFFFC00u) | (unsigned)j);
}

__device__ inline unsigned bf16rne(float x) {
    unsigned u = __float_as_uint(x);
    return (u + 0x7FFFu + ((u >> 16) & 1u)) >> 16;
}
__device__ inline float bflo(unsigned q) { return __uint_as_float(q << 16); }
__device__ inline float bfhi(unsigned q) { return __uint_as_float(q & 0xFFFF0000u); }

// ---------------- K1: a = l2n(kp1_desc) fp32 + bf16 copy + visibility ----------------
__global__ __launch_bounds__(64) void k_prep(const float* __restrict__ desc,
                                             const float* __restrict__ kp1,
                                             const float* __restrict__ homo,
                                             float* __restrict__ a,
                                             unsigned* __restrict__ aB,   // (B,N,64) packed bf16
                                             float* __restrict__ vis) {
    int row = blockIdx.x;
    int l = threadIdx.x;
    const float2* src = (const float2*)(desc + (size_t)row * C_DIM);
    float2 v = src[l];
    float ss = wsum(v.x * v.x + v.y * v.y);
    float nrm = sqrtf(ss) + EPSV;
    float a0 = v.x / nrm, a1 = v.y / nrm;
    ((float2*)(a + (size_t)row * C_DIM))[l] = make_float2(a0, a1);
    aB[(size_t)row * 64 + l] = bf16rne(a0) | (bf16rne(a1) << 16);
    if (l == 0) {
        int b = row >> 10;
        float x = kp1[(size_t)row * 2];
        float y = kp1[(size_t)row * 2 + 1];
        const float* h = homo + b * 9;
        float u = h[0] * x + h[1] * y + h[2];
        float vv = h[3] * x + h[4] * y + h[5];
        float w = h[6] * x + h[7] * y + h[8];
        float wx_ = u / (w + EPSV);
        float wy_ = vv / (w + EPSV);
        float viz = (wx_ >= 0.f && wx_ <= (float)(HW_ - 1) &&
                     wy_ >= 0.f && wy_ <= (float)(HW_ - 1)) ? 1.f : 0.f;
        vis[row] = viz;
    }
}

// ---------------- K2: transpose desc2 (B,C,H,W) fp32 -> (B,H,W,C) packed bf16 ----------------
__global__ __launch_bounds__(256) void k_tr(const float* __restrict__ d2,
                                            unsigned int* __restrict__ d2t) {
    __shared__ float tile[64 * 65];
    int by = blockIdx.z;                 // b*256 + y
    int b = by >> 8, y = by & 255;
    int c0 = blockIdx.y * 64;
    int x0 = blockIdx.x * 64;
    int t = threadIdx.x;
    int tx = t & 63, tq = t >> 6;
#pragma unroll
    for (int i = 0; i < 16; ++i) {
        int c = 4 * i + tq;
        tile[c * 65 + tx] = d2[(size_t)((b * C_DIM + c0 + c) * HW_ + y) * HW_ + x0 + tx];
    }
    __syncthreads();
    int u = t & 31, xq = t >> 5;
#pragma unroll
    for (int i = 0; i < 8; ++i) {
        int x = 8 * i + xq;
        unsigned b0 = bf16rne(tile[(2 * u) * 65 + x]);
        unsigned b1 = bf16rne(tile[(2 * u + 1) * 65 + x]);
        d2t[(size_t)((b * HW_ + y) * HW_ + x0 + x) * 64 + (c0 >> 1) + u] = b0 | (b1 << 16);
    }
}

// ---------------- K3: fused wa (id<4096) + gd (id>=4096) gather -> bf16 operands ----------------
__global__ __launch_bounds__(64) void k_gather(const float* __restrict__ wkp,
                                               const unsigned int* __restrict__ d2t,
                                               const float* __restrict__ a,
                                               unsigned* __restrict__ waB,  // (B,N,64) packed bf16
                                               unsigned* __restrict__ gdB,  // (B,M,64) packed bf16
                                               float* __restrict__ pos) {
    int id = blockIdx.x;
    int l = threadIdx.x;
    if (id < BATCH * N_KP) {
        int row = id;
        int b = row >> 10;
        float px = wkp[(size_t)row * 2];
        float py = wkp[(size_t)row * 2 + 1];
        float x = fminf(fmaxf(px, 0.f), (float)(HW_ - 1));
        float y = fminf(fmaxf(py, 0.f), (float)(HW_ - 1));
        float x0f = floorf(x), y0f = floorf(y);
        float wx = x - x0f, wy = y - y0f;
        int x0 = (int)x0f, y0 = (int)y0f;
        int x1 = min(x0 + 1, HW_ - 1), y1 = min(y0 + 1, HW_ - 1);
        float w00 = (1.f - wy) * (1.f - wx);
        float w01 = (1.f - wy) * wx;
        float w10 = wy * (1.f - wx);
        float w11 = wy * wx;
        const unsigned* P = d2t + (size_t)b * HW_ * HW_ * 64;
        unsigned q00 = P[(size_t)(y0 * HW_ + x0) * 64 + l];
        unsigned q01 = P[(size_t)(y0 * HW_ + x1) * 64 + l];
        unsigned q10 = P[(size_t)(y1 * HW_ + x0) * 64 + l];
        unsigned q11 = P[(size_t)(y1 * HW_ + x1) * 64 + l];
        float v0 = bflo(q00) * w00 + bflo(q01) * w01 + bflo(q10) * w10 + bflo(q11) * w11;
        float v1 = bfhi(q00) * w00 + bfhi(q01) * w01 + bfhi(q10) * w10 + bfhi(q11) * w11;
        float ss = wsum(v0 * v0 + v1 * v1);
        float nrm = sqrtf(ss) + EPSV;
        float wv0 = v0 / nrm, wv1 = v1 / nrm;
        waB[(size_t)row * 64 + l] = bf16rne(wv0) | (bf16rne(wv1) << 16);
        float2 av = ((const float2*)(a + (size_t)row * C_DIM))[l];
        float d0 = av.x - wv0, d1 = av.y - wv1;
        float pp = wsum(d0 * d0 + d1 * d1);
        if (l == 0) pos[row] = sqrtf(pp);
    } else {
        int idx = id - BATCH * N_KP;
        int b = idx >> 10, m = idx & 1023;
        int x0 = (m & 31) * 8 + 4;       // exact-integer grid center -> pure lattice read
        int y0 = (m >> 5) * 8 + 4;
        const unsigned* P = d2t + (size_t)b * HW_ * HW_ * 64;
        unsigned q = P[(size_t)(y0 * HW_ + x0) * 64 + l];
        float v0 = bflo(q), v1 = bfhi(q);
        float ss = wsum(v0 * v0 + v1 * v1);
        float nrm = sqrtf(ss) + EPSV;
        gdB[(size_t)idx * 64 + l] = bf16rne(v0 / nrm) | (bf16rne(v1 / nrm) << 16);
    }
}

// ---------------- K4: MFMA distance matrix -> global ----------------
// z==0: neg (A=aB, G=gdB);  z==1: d2m (A=waB, G=waB)
// Wave: 16 rows x 64 cols (4 MFMA tiles), block: 4 waves = 16 x 256.
__global__ __launch_bounds__(256, 4) void k_dist(const unsigned* __restrict__ aB,
                                                 const unsigned* __restrict__ waB,
                                                 const unsigned* __restrict__ gdB,
                                                 const float* __restrict__ wkp,
                                                 float* __restrict__ mat) {
    int zsel = blockIdx.z;
    int t = threadIdx.x;
    int lane = t & 63, w = t >> 6;
    int m = lane & 15, q = lane >> 4;           // A-frag row / B-frag col = m; k-quad = q
    int rowT = blockIdx.y;                      // 0..255 (16-row tiles over B*N)
    int b = rowT >> 6;
    int n0 = (rowT & 63) * 16;
    int colBase = blockIdx.x * 256 + w * 64;
    const short* A = (const short*)(zsel == 0 ? aB : waB);
    const short* G = (const short*)(zsel == 0 ? gdB : waB);
    const short* Ar = A + ((size_t)(b * N_KP + n0 + m) * C_DIM + q * 8);
    const short* Gb = G + ((size_t)b * N_KP) * C_DIM + q * 8;
    f32x4 acc[4];
#pragma unroll
    for (int ct = 0; ct < 4; ++ct) acc[ct] = f32x4{0.f, 0.f, 0.f, 0.f};
#pragma unroll
    for (int c = 0; c < C_DIM; c += 32) {
        short8 af = *(const short8*)(Ar + c);
#pragma unroll
        for (int ct = 0; ct < 4; ++ct) {
            short8 bf = *(const short8*)(Gb + (size_t)(colBase + ct * 16 + m) * C_DIM + c);
            acc[ct] = __builtin_amdgcn_mfma_f32_16x16x32_bf16(af, bf, acc[ct], 0, 0, 0);
        }
    }
    // D layout: col = colBase+ct*16+m, row(in-tile) = q*4+r  [m89-verified]
    float2 wrow[4];
#pragma unroll
    for (int r = 0; r < 4; ++r)
        wrow[r] = ((const float2*)wkp)[b * N_KP + n0 + q * 4 + r];
    float* out = mat + (size_t)(zsel * BATCH + b) * N_KP * 1024;
#pragma unroll
    for (int ct = 0; ct < 4; ++ct) {
        int j = colBase + ct * 16 + m;
        float cx, cy;
        if (zsel == 0) {
            cx = (float)(j & 31) * 8.0f + 4.0f;
            cy = (float)(j >> 5) * 8.0f + 4.0f;
        } else {
            float2 wj = ((const float2*)wkp)[b * N_KP + j];
            cx = wj.x; cy = wj.y;
        }
#pragma unroll
        for (int r = 0; r < 4; ++r) {
            int n = n0 + q * 4 + r;
            float d = sqrtf(fmaxf(2.f - 2.f * acc[ct][r], 0.f) + EPSV);
            float dx = wrow[r].x - cx, dy = wrow[r].y - cy;
            if (dx * dx + dy * dy < 256.f || (zsel == 1 && n == j)) d = BIGV;
            out[(size_t)n * 1024 + j] = d;
        }
    }
}

// ---------------- K5: selection + per-row loss -> plain stores ----------------
__global__ __launch_bounds__(256) void k_sel(const float* __restrict__ mat,
                                             const float* __restrict__ a,
                                             const float* __restrict__ pos,
                                             const float* __restrict__ vis,
                                             float* __restrict__ fos_row,
                                             float* __restrict__ sos_row) {
    int zsel = blockIdx.y;
    int r4 = blockIdx.x * 4 + (threadIdx.x >> 6);   // row in [0,4096)
    int b = r4 >> 10;
    int l = threadIdx.x & 63;
    const float4* dr = (const float4*)(mat + (size_t)(zsel * BATCH * N_KP + r4) * 1024);
    float s8[8];
#pragma unroll
    for (int k = 0; k < 8; ++k) s8[k] = 1e30f;
    if (zsel == 0) {
        float4 v0 = dr[l], v1 = dr[l + 64], v2 = dr[l + 128], v3 = dr[l + 192];
        ins8(s8, v0.x); ins8(s8, v0.y); ins8(s8, v0.z); ins8(s8, v0.w);
        ins8(s8, v1.x); ins8(s8, v1.y); ins8(s8, v1.z); ins8(s8, v1.w);
        ins8(s8, v2.x); ins8(s8, v2.y); ins8(s8, v2.z); ins8(s8, v2.w);
        ins8(s8, v3.x); ins8(s8, v3.y); ins8(s8, v3.z); ins8(s8, v3.w);
        merge64(s8);
        if (l == 0) {
            float p = pos[r4];
            float sum = 0.f;
#pragma unroll
            for (int q = 0; q < 8; ++q) sum += fmaxf(p - s8[q] + 1.0f, 0.f);
            fos_row[r4] = sum * vis[r4];
        }
    } else {
#pragma unroll
        for (int k = 0; k < 4; ++k) {
            float4 v = dr[l + 64 * k];
            int j = 4 * (l + 64 * k);
            ins8(s8, packkey(v.x, j));
            ins8(s8, packkey(v.y, j + 1));
            ins8(s8, packkey(v.z, j + 2));
            ins8(s8, packkey(v.w, j + 3));
        }
        merge64(s8);
        float2 av = ((const float2*)(a + (size_t)r4 * C_DIM))[l];
        float dot[8];
#pragma unroll
        for (int q = 0; q < 8; ++q) {
            int j = (int)(__float_as_uint(s8[q]) & 1023u);
            float2 jv = ((const float2*)(a + (size_t)(b * N_KP + j) * C_DIM))[l];
            dot[q] = av.x * jv.x + av.y * jv.y;
        }
#pragma unroll
        for (int q = 0; q < 8; ++q) dot[q] = wsum(dot[q]);
        float ss2 = 0.f;
#pragma unroll
        for (int q = 0; q < 8; ++q) {
            float d2s = __uint_as_float(__float_as_uint(s8[q]) & 0xFFFFFC00u);
            float d1 = sqrtf(fmaxf(2.f - 2.f * dot[q], 0.f) + EPSV);
            float okv = (d2s < 5.0f) ? 1.f : 0.f;
            float diff = (d1 - d2s) * okv;
            ss2 += diff * diff;
        }
        if (l == 0) sos_row[r4] = sqrtf(ss2 + EPSV) * vis[r4];
    }
}

// ---------------- K6: deterministic reduction + finalize (single block) ----------------
__global__ __launch_bounds__(1024) void k_red(const float* __restrict__ vis,
                                              const float* __restrict__ fos_row,
                                              const float* __restrict__ sos_row,
                                              float* __restrict__ out) {
    __shared__ float sb[3][16];
    int t = threadIdx.x;
    float sv = 0.f, sf = 0.f, ss = 0.f;
    for (int i = t; i < BATCH * N_KP; i += 1024) {
        sv += vis[i];
        sf += fos_row[i];
        ss += sos_row[i];
    }
    sv = wsum(sv); sf = wsum(sf); ss = wsum(ss);
    int w = t >> 6, l = t & 63;
    if (l == 0) { sb[0][w] = sv; sb[1][w] = sf; sb[2][w] = ss; }
    __syncthreads();
    if (t == 0) {
        float cv = 0.f, cf = 0.f, cs = 0.f;
#pragma unroll
        for (int i = 0; i < 16; ++i) { cv += sb[0][i]; cf += sb[1][i]; cs += sb[2][i]; }
        float cnt = fmaxf(cv, 1.0f);
        out[0] = cf / (cnt * 8.0f) + cs / cnt;
    }
}

extern "C" void kernel_launch(void* const* d_in, const int* in_sizes, int n_in,
                              void* d_out, int out_size, void* d_ws, size_t ws_size,
                              hipStream_t stream) {
    (void)in_sizes; (void)n_in; (void)out_size; (void)ws_size;
    const float* kp1   = (const float*)d_in[0];
    const float* wkp   = (const float*)d_in[1];
    const float* kdesc = (const float*)d_in[2];
    const float* desc2 = (const float*)d_in[3];
    const float* homo  = (const float*)d_in[4];

    float* ws  = (float*)d_ws;
    float* a   = ws + 16;                               // (B,N,C) fp32, 2 MB
    float* pos = a + (size_t)BATCH * N_KP * C_DIM;
    float* vis = pos + BATCH * N_KP;
    float* fos_row = vis + BATCH * N_KP;
    float* sos_row = fos_row + BATCH * N_KP;
    unsigned* aB  = (unsigned*)(sos_row + BATCH * N_KP);        // (B,N,64) bf16x2, 1 MB
    unsigned* waB = aB + (size_t)BATCH * N_KP * 64;             // 1 MB
    unsigned* gdB = waB + (size_t)BATCH * N_KP * 64;            // 1 MB
    unsigned* d2t = gdB + (size_t)BATCH * M_CELLS * 64;         // (B,H,W,64) bf16x2, 64 MB
    float* mat = (float*)(d2t + (size_t)BATCH * HW_ * HW_ * 64); // (2,B,N,1024) fp32, 32 MB

    k_prep<<<BATCH * N_KP, 64, 0, stream>>>(kdesc, kp1, homo, a, aB, vis);
    k_tr<<<dim3(HW_ / 64, C_DIM / 64, BATCH * HW_), 256, 0, stream>>>(desc2, d2t);
    k_gather<<<2 * BATCH * N_KP, 64, 0, stream>>>(wkp, d2t, a, waB, gdB, pos);
    k_dist<<<dim3(4, 256, 2), 256, 0, stream>>>(aB, waB, gdB, wkp, mat);
    k_sel<<<dim3(N_KP * BATCH / 4, 2), 256, 0, stream>>>(mat, a, pos, vis, fos_row, sos_row);
    k_red<<<1, 1024, 0, stream>>>(vis, fos_row, sos_row, (float*)d_out);
}